// Round 14
// baseline (776.989 us; speedup 1.0000x reference)
//
#include <hip/hip_runtime.h>
#include <hip/hip_fp16.h>
#include <hip/hip_cooperative_groups.h>

namespace cg = cooperative_groups;

#define EMB      128
#define NUSERS   80000
#define NITEMS   40000
#define NNODES   120000
#define NNZV     600000
#define BATCHN   4096
#define WELL     24          // P(Poisson(5) > 24) ~ 1e-10 per row

#define MBLK     512         // threads per block everywhere in build/mega
#define MGRID    512         // cooperative grid: 2 blocks/CU x 256 CU (VGPR<=128 guaranteed fit)

#define NBKT     256         // buckets = row >> 9 (235 used)
#define BSHIFT   9
#define EPB      (MBLK * 8)                    // 4096 edges per bucket slice
#define NBBLK    ((NNZV + EPB - 1) / EPB)      // 147 bucket slices
#define SCAP     48          // slots/(slice,bucket): mean 17.4, P(>48) ~ 5e-9 total
#define NBUCK    ((NNODES + 511) >> 9)         // 235

typedef unsigned int u32;

// ---- bf16x2 pack/unpack (RNE) ----
__device__ __forceinline__ u32 pack2(float lo, float hi) {
    u32 a = __float_as_uint(lo), b = __float_as_uint(hi);
    a = (a + 0x7FFFu + ((a >> 16) & 1u)) >> 16;
    b = (b + 0x7FFFu + ((b >> 16) & 1u)) >> 16;
    return a | (b << 16);
}
__device__ __forceinline__ float lo2f(u32 u) { return __uint_as_float(u << 16); }
__device__ __forceinline__ float hi2f(u32 u) { return __uint_as_float(u & 0xFFFF0000u); }
__device__ __forceinline__ float val15(u32 w) {
    return __half2float(__ushort_as_half((unsigned short)(w & 0x7FFFu)));
}

#define CVT_N   (NNODES * EMB / 8)             // 1.92M convert items (8 floats each)

// ---------------- shared building blocks ----------------
__device__ __forceinline__ void do_convert(
    int t, const float* __restrict__ ue, const float* __restrict__ ie,
    u32* __restrict__ ego)
{
    const float4* s = (t < NUSERS * EMB / 8)
        ? ((const float4*)ue) + (size_t)t * 2
        : ((const float4*)ie) + ((size_t)t - NUSERS * EMB / 8) * 2;
    float4 a = s[0], b = s[1];
    uint4 o;
    o.x = pack2(a.x, a.y); o.y = pack2(a.z, a.w);
    o.z = pack2(b.x, b.y); o.w = pack2(b.z, b.w);
    ((uint4*)ego)[t] = o;
}

__device__ __forceinline__ void do_bucket(
    int blk, int tid,
    const int* __restrict__ row, const int* __restrict__ col,
    const float* __restrict__ val,
    int* __restrict__ scnt, uint2* __restrict__ bkt)
{
    __shared__ u32 hist[NBKT];
    if (tid < NBKT) hist[tid] = 0;
    __syncthreads();
    u32 packA[8], cc[8], rk[8];
    int bb[8];
    #pragma unroll
    for (int k = 0; k < 8; ++k) {
        int e = blk * EPB + k * MBLK + tid;
        bool ok = e < NNZV;
        int r  = ok ? row[e] : 0;
        int c  = ok ? col[e] : 0;
        float v = ok ? val[e] : 0.f;
        packA[k] = ((u32)r << 15)
                 | (u32)(__half_as_ushort(__float2half_rn(v)) & 0x7FFF);
        cc[k] = (u32)c;
        bb[k] = ok ? (r >> BSHIFT) : -1;
        rk[k] = ok ? atomicAdd(&hist[r >> BSHIFT], 1u) : 0u;
    }
    __syncthreads();
    #pragma unroll
    for (int k = 0; k < 8; ++k) {
        if (bb[k] >= 0 && rk[k] < SCAP)
            bkt[((size_t)blk * NBKT + bb[k]) * SCAP + rk[k]]
                = make_uint2(packA[k], cc[k]);
    }
    if (tid < NBKT)
        scnt[blk * NBKT + tid] = min(hist[tid], (u32)SCAP);
}

__device__ __forceinline__ void do_ell(
    int b, int tid,
    const int* __restrict__ scnt, const uint2* __restrict__ bkt,
    u32* __restrict__ ell, int* __restrict__ counts)
{
    __shared__ int cnt[512];
    __shared__ int scn[NBBLK];
    if (tid < 512) cnt[tid] = 0;
    if (tid < NBBLK) scn[tid] = scnt[tid * NBKT + b];
    __syncthreads();
    for (int idx = tid; idx < NBBLK * SCAP; idx += MBLK) {
        int s = idx / SCAP;
        int i = idx - s * SCAP;
        if (i < scn[s]) {
            uint2 e = bkt[((size_t)s * NBKT + b) * SCAP + i];
            u32 r = e.x >> 15;
            int p = atomicAdd(&cnt[r & 511], 1);
            if (p < WELL)
                ell[(size_t)r * WELL + p] = (e.y << 15) | (e.x & 0x7FFFu);
        }
    }
    __syncthreads();
    int gr = (b << BSHIFT) + tid;
    if (tid < 512 && gr < NNODES) counts[gr] = cnt[tid];
}

// ---------------- 8-slot gather (single row, self-contained wait)
__device__ __forceinline__ void gath8(
    const u32* __restrict__ src, const u32* __restrict__ e, u32 voff,
    int k0, int c, float& a0, float& a1)
{
    u32 w0 = e[0], w1 = e[1], w2 = e[2], w3 = e[3];
    u32 w4 = e[4], w5 = e[5], w6 = e[6], w7 = e[7];
    const u32* p0 = src + ((size_t)min(w0 >> 15, NNODES - 1u) << 6);
    const u32* p1 = src + ((size_t)min(w1 >> 15, NNODES - 1u) << 6);
    const u32* p2 = src + ((size_t)min(w2 >> 15, NNODES - 1u) << 6);
    const u32* p3 = src + ((size_t)min(w3 >> 15, NNODES - 1u) << 6);
    const u32* p4 = src + ((size_t)min(w4 >> 15, NNODES - 1u) << 6);
    const u32* p5 = src + ((size_t)min(w5 >> 15, NNODES - 1u) << 6);
    const u32* p6 = src + ((size_t)min(w6 >> 15, NNODES - 1u) << 6);
    const u32* p7 = src + ((size_t)min(w7 >> 15, NNODES - 1u) << 6);
    u32 x0, x1, x2, x3, x4, x5, x6, x7;
    asm volatile(
        "global_load_dword %[x0], %[v], %[s0]\n\t"
        "global_load_dword %[x1], %[v], %[s1]\n\t"
        "global_load_dword %[x2], %[v], %[s2]\n\t"
        "global_load_dword %[x3], %[v], %[s3]\n\t"
        "global_load_dword %[x4], %[v], %[s4]\n\t"
        "global_load_dword %[x5], %[v], %[s5]\n\t"
        "global_load_dword %[x6], %[v], %[s6]\n\t"
        "global_load_dword %[x7], %[v], %[s7]\n\t"
        "s_waitcnt vmcnt(0)"
        : [x0]"=&v"(x0), [x1]"=&v"(x1), [x2]"=&v"(x2), [x3]"=&v"(x3),
          [x4]"=&v"(x4), [x5]"=&v"(x5), [x6]"=&v"(x6), [x7]"=&v"(x7)
        : [v]"v"(voff),
          [s0]"s"(p0), [s1]"s"(p1), [s2]"s"(p2), [s3]"s"(p3),
          [s4]"s"(p4), [s5]"s"(p5), [s6]"s"(p6), [s7]"s"(p7)
        : "memory");
    float v0 = (k0 + 0 < c) ? val15(w0) : 0.f;
    float v1 = (k0 + 1 < c) ? val15(w1) : 0.f;
    float v2 = (k0 + 2 < c) ? val15(w2) : 0.f;
    float v3 = (k0 + 3 < c) ? val15(w3) : 0.f;
    float v4 = (k0 + 4 < c) ? val15(w4) : 0.f;
    float v5 = (k0 + 5 < c) ? val15(w5) : 0.f;
    float v6 = (k0 + 6 < c) ? val15(w6) : 0.f;
    float v7 = (k0 + 7 < c) ? val15(w7) : 0.f;
    a0 += v0*lo2f(x0) + v1*lo2f(x1) + v2*lo2f(x2) + v3*lo2f(x3)
        + v4*lo2f(x4) + v5*lo2f(x5) + v6*lo2f(x6) + v7*lo2f(x7);
    a1 += v0*hi2f(x0) + v1*hi2f(x1) + v2*hi2f(x2) + v3*hi2f(x3)
        + v4*hi2f(x4) + v5*hi2f(x5) + v6*hi2f(x6) + v7*hi2f(x7);
}

// ---------------- two rows x 8 slots, 16 loads in flight, one wait
// asm1 issues row-A loads (no wait); asm2 issues row-B loads + vmcnt(0),
// with row-A regs threaded through as "+v" so uses can't be hoisted above it.
__device__ __forceinline__ void gath8x2(
    const u32* __restrict__ src, const u32* __restrict__ eA,
    const u32* __restrict__ eB, u32 voff, int cA, int cB,
    float& a0, float& a1, float& b0, float& b1)
{
    u32 wa0=eA[0], wa1=eA[1], wa2=eA[2], wa3=eA[3];
    u32 wa4=eA[4], wa5=eA[5], wa6=eA[6], wa7=eA[7];
    u32 wb0=eB[0], wb1=eB[1], wb2=eB[2], wb3=eB[3];
    u32 wb4=eB[4], wb5=eB[5], wb6=eB[6], wb7=eB[7];
    const u32* pa0 = src + ((size_t)min(wa0 >> 15, NNODES - 1u) << 6);
    const u32* pa1 = src + ((size_t)min(wa1 >> 15, NNODES - 1u) << 6);
    const u32* pa2 = src + ((size_t)min(wa2 >> 15, NNODES - 1u) << 6);
    const u32* pa3 = src + ((size_t)min(wa3 >> 15, NNODES - 1u) << 6);
    const u32* pa4 = src + ((size_t)min(wa4 >> 15, NNODES - 1u) << 6);
    const u32* pa5 = src + ((size_t)min(wa5 >> 15, NNODES - 1u) << 6);
    const u32* pa6 = src + ((size_t)min(wa6 >> 15, NNODES - 1u) << 6);
    const u32* pa7 = src + ((size_t)min(wa7 >> 15, NNODES - 1u) << 6);
    const u32* pb0 = src + ((size_t)min(wb0 >> 15, NNODES - 1u) << 6);
    const u32* pb1 = src + ((size_t)min(wb1 >> 15, NNODES - 1u) << 6);
    const u32* pb2 = src + ((size_t)min(wb2 >> 15, NNODES - 1u) << 6);
    const u32* pb3 = src + ((size_t)min(wb3 >> 15, NNODES - 1u) << 6);
    const u32* pb4 = src + ((size_t)min(wb4 >> 15, NNODES - 1u) << 6);
    const u32* pb5 = src + ((size_t)min(wb5 >> 15, NNODES - 1u) << 6);
    const u32* pb6 = src + ((size_t)min(wb6 >> 15, NNODES - 1u) << 6);
    const u32* pb7 = src + ((size_t)min(wb7 >> 15, NNODES - 1u) << 6);
    u32 x0, x1, x2, x3, x4, x5, x6, x7;
    u32 y0, y1, y2, y3, y4, y5, y6, y7;
    asm volatile(
        "global_load_dword %[x0], %[v], %[s0]\n\t"
        "global_load_dword %[x1], %[v], %[s1]\n\t"
        "global_load_dword %[x2], %[v], %[s2]\n\t"
        "global_load_dword %[x3], %[v], %[s3]\n\t"
        "global_load_dword %[x4], %[v], %[s4]\n\t"
        "global_load_dword %[x5], %[v], %[s5]\n\t"
        "global_load_dword %[x6], %[v], %[s6]\n\t"
        "global_load_dword %[x7], %[v], %[s7]"
        : [x0]"=&v"(x0), [x1]"=&v"(x1), [x2]"=&v"(x2), [x3]"=&v"(x3),
          [x4]"=&v"(x4), [x5]"=&v"(x5), [x6]"=&v"(x6), [x7]"=&v"(x7)
        : [v]"v"(voff),
          [s0]"s"(pa0), [s1]"s"(pa1), [s2]"s"(pa2), [s3]"s"(pa3),
          [s4]"s"(pa4), [s5]"s"(pa5), [s6]"s"(pa6), [s7]"s"(pa7));
    asm volatile(
        "global_load_dword %[y0], %[v], %[s0]\n\t"
        "global_load_dword %[y1], %[v], %[s1]\n\t"
        "global_load_dword %[y2], %[v], %[s2]\n\t"
        "global_load_dword %[y3], %[v], %[s3]\n\t"
        "global_load_dword %[y4], %[v], %[s4]\n\t"
        "global_load_dword %[y5], %[v], %[s5]\n\t"
        "global_load_dword %[y6], %[v], %[s6]\n\t"
        "global_load_dword %[y7], %[v], %[s7]\n\t"
        "s_waitcnt vmcnt(0)"
        : [y0]"=&v"(y0), [y1]"=&v"(y1), [y2]"=&v"(y2), [y3]"=&v"(y3),
          [y4]"=&v"(y4), [y5]"=&v"(y5), [y6]"=&v"(y6), [y7]"=&v"(y7),
          [x0]"+v"(x0), [x1]"+v"(x1), [x2]"+v"(x2), [x3]"+v"(x3),
          [x4]"+v"(x4), [x5]"+v"(x5), [x6]"+v"(x6), [x7]"+v"(x7)
        : [v]"v"(voff),
          [s0]"s"(pb0), [s1]"s"(pb1), [s2]"s"(pb2), [s3]"s"(pb3),
          [s4]"s"(pb4), [s5]"s"(pb5), [s6]"s"(pb6), [s7]"s"(pb7));
    float va0 = (0 < cA) ? val15(wa0) : 0.f;
    float va1 = (1 < cA) ? val15(wa1) : 0.f;
    float va2 = (2 < cA) ? val15(wa2) : 0.f;
    float va3 = (3 < cA) ? val15(wa3) : 0.f;
    float va4 = (4 < cA) ? val15(wa4) : 0.f;
    float va5 = (5 < cA) ? val15(wa5) : 0.f;
    float va6 = (6 < cA) ? val15(wa6) : 0.f;
    float va7 = (7 < cA) ? val15(wa7) : 0.f;
    float vb0 = (0 < cB) ? val15(wb0) : 0.f;
    float vb1 = (1 < cB) ? val15(wb1) : 0.f;
    float vb2 = (2 < cB) ? val15(wb2) : 0.f;
    float vb3 = (3 < cB) ? val15(wb3) : 0.f;
    float vb4 = (4 < cB) ? val15(wb4) : 0.f;
    float vb5 = (5 < cB) ? val15(wb5) : 0.f;
    float vb6 = (6 < cB) ? val15(wb6) : 0.f;
    float vb7 = (7 < cB) ? val15(wb7) : 0.f;
    a0 += va0*lo2f(x0) + va1*lo2f(x1) + va2*lo2f(x2) + va3*lo2f(x3)
        + va4*lo2f(x4) + va5*lo2f(x5) + va6*lo2f(x6) + va7*lo2f(x7);
    a1 += va0*hi2f(x0) + va1*hi2f(x1) + va2*hi2f(x2) + va3*hi2f(x3)
        + va4*hi2f(x4) + va5*hi2f(x5) + va6*hi2f(x6) + va7*hi2f(x7);
    b0 += vb0*lo2f(y0) + vb1*lo2f(y1) + vb2*lo2f(y2) + vb3*lo2f(y3)
        + vb4*lo2f(y4) + vb5*lo2f(y5) + vb6*lo2f(y6) + vb7*lo2f(y7);
    b1 += vb0*hi2f(y0) + vb1*hi2f(y1) + vb2*hi2f(y2) + vb3*hi2f(y3)
        + vb4*hi2f(y4) + vb5*hi2f(y5) + vb6*hi2f(y6) + vb7*hi2f(y7);
}

__device__ __forceinline__ float2 row_accum(
    int r, u32 voff, const int* __restrict__ counts,
    const u32* __restrict__ ell, const u32* __restrict__ src)
{
    const u32* e = ell + (size_t)r * WELL;
    int c = min(counts[r], WELL);
    float a0 = 0.f, a1 = 0.f;
    gath8(src, e, voff, 0, c, a0, a1);
    if (c > 8) {
        gath8(src, e + 8, voff, 8, c, a0, a1);
        if (c > 16)
            gath8(src, e + 16, voff, 16, c, a0, a1);
    }
    return make_float2(a0, a1);
}

__device__ __forceinline__ void row2(
    int rA, int rB, u32 voff, const int* __restrict__ counts,
    const u32* __restrict__ ell, const u32* __restrict__ src,
    float2& A, float2& B)
{
    const u32* eA = ell + (size_t)rA * WELL;
    const u32* eB = ell + (size_t)rB * WELL;
    int cA = min(counts[rA], WELL);
    int cB = min(counts[rB], WELL);
    float a0 = 0.f, a1 = 0.f, b0 = 0.f, b1 = 0.f;
    gath8x2(src, eA, eB, voff, cA, cB, a0, a1, b0, b1);
    if (cA > 8) {
        gath8(src, eA + 8, voff, 8, cA, a0, a1);
        if (cA > 16) gath8(src, eA + 16, voff, 16, cA, a0, a1);
    }
    if (cB > 8) {
        gath8(src, eB + 8, voff, 8, cB, b0, b1);
        if (cB > 16) gath8(src, eB + 16, voff, 16, cB, b0, b1);
    }
    A = make_float2(a0, a1);
    B = make_float2(b0, b1);
}

// ---------------- the one-dispatch cooperative pipeline
#define TOTW (2 * BATCHN + NITEMS + BATCHN)    // 52288 output rows
__global__ __launch_bounds__(MBLK, 4) void mega(
    const int* __restrict__ row, const int* __restrict__ col,
    const float* __restrict__ val,
    const float* __restrict__ ue, const float* __restrict__ ie,
    const int* __restrict__ users, const int* __restrict__ pos,
    const int* __restrict__ neg,
    int* __restrict__ scnt, uint2* __restrict__ bkt,
    u32* __restrict__ ell, int* __restrict__ counts,
    u32* __restrict__ ego, u32* __restrict__ h1, u32* __restrict__ h2,
    float* __restrict__ out)
{
    cg::grid_group grid = cg::this_grid();
    const int tid = threadIdx.x;

    // ---- phase 0: bucket scatter (blocks 0..NBBLK) || bf16 convert (rest)
    if (blockIdx.x < NBBLK) {
        do_bucket(blockIdx.x, tid, row, col, val, scnt, bkt);
    } else {
        int stride = (gridDim.x - NBBLK) * MBLK;
        for (int t = (blockIdx.x - NBBLK) * MBLK + tid; t < CVT_N; t += stride)
            do_convert(t, ue, ie, ego);
    }
    __threadfence();
    grid.sync();

    // ---- phase A: per-bucket ELL build
    if (blockIdx.x < NBUCK)
        do_ell(blockIdx.x, tid, scnt, bkt, ell, counts);
    __threadfence();
    grid.sync();

    const int nw   = (gridDim.x * MBLK) >> 6;
    const int wg   = (blockIdx.x * MBLK + tid) >> 6;
    const int lane = tid & 63;
    const u32 voff = lane * 4;

    // ---- phase B: spmm pass 1 (ego -> h1), 2 rows/wave
    for (int p = wg; p < NNODES / 2; p += nw) {
        int rA = __builtin_amdgcn_readfirstlane(p * 2);
        int rB = rA + 1;
        float2 A, B;
        row2(rA, rB, voff, counts, ell, ego, A, B);
        h1[((size_t)rA << 6) + lane] = pack2(A.x, A.y);
        h1[((size_t)rB << 6) + lane] = pack2(B.x, B.y);
    }
    __threadfence();
    grid.sync();

    // ---- phase C: spmm pass 2 (h1 -> h2), 2 rows/wave
    for (int p = wg; p < NNODES / 2; p += nw) {
        int rA = __builtin_amdgcn_readfirstlane(p * 2);
        int rB = rA + 1;
        float2 A, B;
        row2(rA, rB, voff, counts, ell, h1, A, B);
        h2[((size_t)rA << 6) + lane] = pack2(A.x, A.y);
        h2[((size_t)rB << 6) + lane] = pack2(B.x, B.y);
    }
    __threadfence();
    grid.sync();

    // ---- phase D: pass 3 + finalize + pos/neg gathers (bf16 ego term)
    for (int w0 = wg; w0 < TOTW; w0 += nw) {
        int w = __builtin_amdgcn_readfirstlane(w0);
        int r, d;
        if (w < BATCHN)                   { r = users[w];                 d = w; }
        else if (w < BATCHN + NITEMS)     { int i = w - BATCHN;
                                            r = NUSERS + i;              d = 3 * BATCHN + i; }
        else if (w < 2 * BATCHN + NITEMS) { int i = w - BATCHN - NITEMS;
                                            r = NUSERS + pos[i];         d = BATCHN + i; }
        else                              { int i = w - 2 * BATCHN - NITEMS;
                                            r = NUSERS + neg[i];         d = 2 * BATCHN + i; }
        float2 a = row_accum(r, voff, counts, ell, h2);
        u32 g  = ego[((size_t)r << 6) + lane];
        u32 b1 = h1[((size_t)r << 6) + lane];
        u32 b2 = h2[((size_t)r << 6) + lane];
        float2 o;
        o.x = (lo2f(g) + lo2f(b1) + lo2f(b2) + a.x) * 0.25f;
        o.y = (hi2f(g) + hi2f(b1) + hi2f(b2) + a.y) * 0.25f;
        ((float2*)out + (size_t)d * 64)[lane] = o;
    }
}

// ---------------- fallback (non-cooperative) path: R12-equivalent ----------------
__global__ __launch_bounds__(MBLK) void bucket_convert_sa(
    const int* __restrict__ row, const int* __restrict__ col,
    const float* __restrict__ val,
    int* __restrict__ scnt, uint2* __restrict__ bkt,
    const float* __restrict__ ue, const float* __restrict__ ie,
    u32* __restrict__ ego)
{
    if (blockIdx.x < NBBLK) {
        do_bucket(blockIdx.x, threadIdx.x, row, col, val, scnt, bkt);
    } else {
        int t = (blockIdx.x - NBBLK) * MBLK + threadIdx.x;
        if (t < CVT_N) do_convert(t, ue, ie, ego);
    }
}

__global__ __launch_bounds__(MBLK) void ell_sa(
    const int* __restrict__ scnt, const uint2* __restrict__ bkt,
    u32* __restrict__ ell, int* __restrict__ counts)
{
    do_ell(blockIdx.x, threadIdx.x, scnt, bkt, ell, counts);
}

__global__ __launch_bounds__(256) void spmm_sa(
    const int* __restrict__ counts, const u32* __restrict__ ell,
    const u32* __restrict__ src, u32* __restrict__ dst)
{
    int wid = (blockIdx.x * 256 + threadIdx.x) >> 6;
    int r = __builtin_amdgcn_readfirstlane(wid);
    int lane = threadIdx.x & 63;
    float2 a = row_accum(r, lane * 4, counts, ell, src);
    dst[((size_t)r << 6) + lane] = pack2(a.x, a.y);
}

__global__ __launch_bounds__(256) void fin_sa(
    const int* __restrict__ users, const int* __restrict__ pos,
    const int* __restrict__ neg,
    const int* __restrict__ counts, const u32* __restrict__ ell,
    const u32* __restrict__ ego, const u32* __restrict__ h1,
    const u32* __restrict__ h2, float* __restrict__ out)
{
    int wid = (blockIdx.x * 256 + threadIdx.x) >> 6;
    int w = __builtin_amdgcn_readfirstlane(wid);
    int lane = threadIdx.x & 63;
    int r, d;
    if (w < BATCHN)                   { r = users[w];                 d = w; }
    else if (w < BATCHN + NITEMS)     { int i = w - BATCHN;
                                        r = NUSERS + i;              d = 3 * BATCHN + i; }
    else if (w < 2 * BATCHN + NITEMS) { int i = w - BATCHN - NITEMS;
                                        r = NUSERS + pos[i];         d = BATCHN + i; }
    else                              { int i = w - 2 * BATCHN - NITEMS;
                                        r = NUSERS + neg[i];         d = 2 * BATCHN + i; }
    float2 a = row_accum(r, lane * 4, counts, ell, h2);
    u32 g  = ego[((size_t)r << 6) + lane];
    u32 b1 = h1[((size_t)r << 6) + lane];
    u32 b2 = h2[((size_t)r << 6) + lane];
    float2 o;
    o.x = (lo2f(g) + lo2f(b1) + lo2f(b2) + a.x) * 0.25f;
    o.y = (hi2f(g) + hi2f(b1) + hi2f(b2) + a.y) * 0.25f;
    ((float2*)out + (size_t)d * 64)[lane] = o;
}

extern "C" void kernel_launch(void* const* d_in, const int* in_sizes, int n_in,
                              void* d_out, int out_size, void* d_ws, size_t ws_size,
                              hipStream_t stream)
{
    const int*   users = (const int*)d_in[0];
    const int*   pos   = (const int*)d_in[1];
    const int*   neg   = (const int*)d_in[2];
    const float* ue    = (const float*)d_in[3];
    const float* ie    = (const float*)d_in[4];
    const int*   arow  = (const int*)d_in[5];
    const int*   acol  = (const int*)d_in[6];
    const float* aval  = (const float*)d_in[7];

    const size_t hU = (size_t)NNODES * 64;        // u32 per bf16 node table
    char* ws = (char*)d_ws;
    u32*   h2     = (u32*)ws;   ws += hU * sizeof(u32);
    u32*   h1     = (u32*)ws;   ws += hU * sizeof(u32);
    u32*   ego    = (u32*)ws;   ws += hU * sizeof(u32);
    u32*   ell    = (u32*)ws;   ws += (size_t)NNODES * WELL * sizeof(u32);
    uint2* bkt    = (uint2*)ws; ws += (size_t)NBBLK * NBKT * SCAP * sizeof(uint2);
    int*   counts = (int*)ws;   ws += NNODES * sizeof(int);
    int*   scnt   = (int*)ws;   ws += NBBLK * NBKT * sizeof(int);
    float* out    = (float*)d_out;

    void* args[] = { (void*)&arow, (void*)&acol, (void*)&aval,
                     (void*)&ue, (void*)&ie,
                     (void*)&users, (void*)&pos, (void*)&neg,
                     (void*)&scnt, (void*)&bkt, (void*)&ell, (void*)&counts,
                     (void*)&ego, (void*)&h1, (void*)&h2, (void*)&out };
    hipError_t ce = hipLaunchCooperativeKernel((void*)mega, dim3(MGRID),
                                               dim3(MBLK), args, 0, stream);
    if (ce != hipSuccess) {
        (void)hipGetLastError();   // clear sticky error; run classic pipeline
        int cvgrid = NBBLK + (CVT_N + MBLK - 1) / MBLK;
        bucket_convert_sa<<<cvgrid, MBLK, 0, stream>>>(
            arow, acol, aval, scnt, bkt, ue, ie, ego);
        ell_sa<<<NBUCK, MBLK, 0, stream>>>(scnt, bkt, ell, counts);
        spmm_sa<<<NNODES / 4, 256, 0, stream>>>(counts, ell, ego, h1);
        spmm_sa<<<NNODES / 4, 256, 0, stream>>>(counts, ell, h1, h2);
        fin_sa<<<TOTW / 4, 256, 0, stream>>>(
            users, pos, neg, counts, ell, ego, h1, h2, out);
    }
}

// Round 15
// 108.181 us; speedup vs baseline: 7.1823x; 7.1823x over previous
//
#include <hip/hip_runtime.h>
#include <hip/hip_fp16.h>

#define EMB      128
#define NUSERS   80000
#define NITEMS   40000
#define NNODES   120000
#define NNZV     600000
#define BATCHN   4096
#define WELL     24          // P(Poisson(5) > 24) ~ 1e-10 per row

#define NBKT     256         // buckets = row >> 9 (235 used)
#define BSHIFT   9
#define EPB      8192        // edges per bucket block (1024 thr x 8)
#define NBBLK    ((NNZV + EPB - 1) / EPB)      // 74 bucket slices
#define SCAP     80          // slots per (slice,bucket); mean 35, P(>80)~6e-10
#define NBUCK    ((NNODES + 511) >> 9)         // 235

typedef unsigned int u32;

// ---- bf16x2 pack/unpack (RNE) ----
__device__ __forceinline__ u32 pack2(float lo, float hi) {
    u32 a = __float_as_uint(lo), b = __float_as_uint(hi);
    a = (a + 0x7FFFu + ((a >> 16) & 1u)) >> 16;
    b = (b + 0x7FFFu + ((b >> 16) & 1u)) >> 16;
    return a | (b << 16);
}
__device__ __forceinline__ float lo2f(u32 u) { return __uint_as_float(u << 16); }
__device__ __forceinline__ float hi2f(u32 u) { return __uint_as_float(u & 0xFFFF0000u); }
__device__ __forceinline__ float val15(u32 w) {
    return __half2float(__ushort_as_half((unsigned short)(w & 0x7FFFu)));
}

#define CVT_N   (NNODES * EMB / 8)             // 1.92M convert items (8 floats each)
#define CVBLKS  ((CVT_N + 1023) / 1024)        // 1875 convert blocks (1024 thr)

// ---------------- phase 1: deterministic bucket scatter || ego convert
// No global atomics, no pre-zeroed global state: each bucket block owns a
// fixed SCAP-slot slice of every bucket; ranks from LDS histogram only.
__global__ __launch_bounds__(1024) void bucket_convert(
    const int* __restrict__ row, const int* __restrict__ col,
    const float* __restrict__ val,
    int* __restrict__ scnt, uint2* __restrict__ bkt,
    const float* __restrict__ ue, const float* __restrict__ ie,
    u32* __restrict__ ego)
{
    if (blockIdx.x < NBBLK) {
        __shared__ u32 hist[NBKT];
        int blk = blockIdx.x;
        int tid = threadIdx.x;
        if (tid < NBKT) hist[tid] = 0;
        __syncthreads();
        u32 packA[8], cc[8], rk[8];
        int bb[8];
        #pragma unroll
        for (int k = 0; k < 8; ++k) {
            int e = blk * EPB + k * 1024 + tid;
            bool ok = e < NNZV;
            int r  = ok ? row[e] : 0;
            int c  = ok ? col[e] : 0;
            float v = ok ? val[e] : 0.f;
            packA[k] = ((u32)r << 15)
                     | (u32)(__half_as_ushort(__float2half_rn(v)) & 0x7FFF);
            cc[k] = (u32)c;
            bb[k] = ok ? (r >> BSHIFT) : -1;
            rk[k] = ok ? atomicAdd(&hist[r >> BSHIFT], 1u) : 0u;
        }
        __syncthreads();
        #pragma unroll
        for (int k = 0; k < 8; ++k) {
            if (bb[k] >= 0 && rk[k] < SCAP)
                bkt[((size_t)blk * NBKT + bb[k]) * SCAP + rk[k]]
                    = make_uint2(packA[k], cc[k]);
        }
        if (tid < NBKT)
            scnt[blk * NBKT + tid] = min(hist[tid], (u32)SCAP);  // coalesced
    } else {
        int t = (blockIdx.x - NBBLK) * 1024 + threadIdx.x;
        if (t >= CVT_N) return;
        const float4* s = (t < NUSERS * EMB / 8)
            ? ((const float4*)ue) + (size_t)t * 2
            : ((const float4*)ie) + ((size_t)t - NUSERS * EMB / 8) * 2;
        float4 a = s[0], b = s[1];
        uint4 o;
        o.x = pack2(a.x, a.y); o.y = pack2(a.z, a.w);
        o.z = pack2(b.x, b.y); o.w = pack2(b.z, b.w);
        ((uint4*)ego)[t] = o;
    }
}

// ---------------- phase 2: one block per bucket -> ELL + dense counts
__global__ __launch_bounds__(1024) void ell_from_buckets(
    const int* __restrict__ scnt, const uint2* __restrict__ bkt,
    u32* __restrict__ ell, int* __restrict__ counts)
{
    __shared__ int cnt[512];
    __shared__ int scn[NBBLK];
    int b = blockIdx.x;
    int tid = threadIdx.x;
    if (tid < 512) cnt[tid] = 0;
    if (tid < NBBLK) scn[tid] = scnt[tid * NBKT + b];
    __syncthreads();
    for (int idx = tid; idx < NBBLK * SCAP; idx += 1024) {
        int s = idx / SCAP;
        int i = idx - s * SCAP;
        if (i < scn[s]) {
            uint2 e = bkt[((size_t)s * NBKT + b) * SCAP + i];
            u32 r = e.x >> 15;
            int p = atomicAdd(&cnt[r & 511], 1);
            if (p < WELL)
                ell[(size_t)r * WELL + p] = (e.y << 15) | (e.x & 0x7FFFu);
        }
    }
    __syncthreads();
    int gr = (b << BSHIFT) + tid;
    if (tid < 512 && gr < NNODES) counts[gr] = cnt[tid];
}

// ---------------- 8-slot gather+accumulate, predicated by row count
// (ELL slots >= c are garbage -> clamp col, zero val)
__device__ __forceinline__ void gath8(
    const u32* __restrict__ src, const u32* __restrict__ e, u32 voff,
    int k0, int c, float& a0, float& a1)
{
    u32 w0 = e[0], w1 = e[1], w2 = e[2], w3 = e[3];
    u32 w4 = e[4], w5 = e[5], w6 = e[6], w7 = e[7];
    const u32* p0 = src + ((size_t)min(w0 >> 15, NNODES - 1u) << 6);
    const u32* p1 = src + ((size_t)min(w1 >> 15, NNODES - 1u) << 6);
    const u32* p2 = src + ((size_t)min(w2 >> 15, NNODES - 1u) << 6);
    const u32* p3 = src + ((size_t)min(w3 >> 15, NNODES - 1u) << 6);
    const u32* p4 = src + ((size_t)min(w4 >> 15, NNODES - 1u) << 6);
    const u32* p5 = src + ((size_t)min(w5 >> 15, NNODES - 1u) << 6);
    const u32* p6 = src + ((size_t)min(w6 >> 15, NNODES - 1u) << 6);
    const u32* p7 = src + ((size_t)min(w7 >> 15, NNODES - 1u) << 6);
    u32 x0, x1, x2, x3, x4, x5, x6, x7;
    asm volatile(
        "global_load_dword %[x0], %[v], %[s0]\n\t"
        "global_load_dword %[x1], %[v], %[s1]\n\t"
        "global_load_dword %[x2], %[v], %[s2]\n\t"
        "global_load_dword %[x3], %[v], %[s3]\n\t"
        "global_load_dword %[x4], %[v], %[s4]\n\t"
        "global_load_dword %[x5], %[v], %[s5]\n\t"
        "global_load_dword %[x6], %[v], %[s6]\n\t"
        "global_load_dword %[x7], %[v], %[s7]\n\t"
        "s_waitcnt vmcnt(0)"
        : [x0]"=&v"(x0), [x1]"=&v"(x1), [x2]"=&v"(x2), [x3]"=&v"(x3),
          [x4]"=&v"(x4), [x5]"=&v"(x5), [x6]"=&v"(x6), [x7]"=&v"(x7)
        : [v]"v"(voff),
          [s0]"s"(p0), [s1]"s"(p1), [s2]"s"(p2), [s3]"s"(p3),
          [s4]"s"(p4), [s5]"s"(p5), [s6]"s"(p6), [s7]"s"(p7)
        : "memory");
    float v0 = (k0 + 0 < c) ? val15(w0) : 0.f;
    float v1 = (k0 + 1 < c) ? val15(w1) : 0.f;
    float v2 = (k0 + 2 < c) ? val15(w2) : 0.f;
    float v3 = (k0 + 3 < c) ? val15(w3) : 0.f;
    float v4 = (k0 + 4 < c) ? val15(w4) : 0.f;
    float v5 = (k0 + 5 < c) ? val15(w5) : 0.f;
    float v6 = (k0 + 6 < c) ? val15(w6) : 0.f;
    float v7 = (k0 + 7 < c) ? val15(w7) : 0.f;
    a0 += v0*lo2f(x0) + v1*lo2f(x1) + v2*lo2f(x2) + v3*lo2f(x3)
        + v4*lo2f(x4) + v5*lo2f(x5) + v6*lo2f(x6) + v7*lo2f(x7);
    a1 += v0*hi2f(x0) + v1*hi2f(x1) + v2*hi2f(x2) + v3*hi2f(x3)
        + v4*hi2f(x4) + v5*hi2f(x5) + v6*hi2f(x6) + v7*hi2f(x7);
}

__device__ __forceinline__ float2 row_accum(
    int r, u32 voff, const int* __restrict__ counts,
    const u32* __restrict__ ell, const u32* __restrict__ src)
{
    const u32* e = ell + (size_t)r * WELL;
    int c = min(counts[r], WELL);
    float a0 = 0.f, a1 = 0.f;
    gath8(src, e, voff, 0, c, a0, a1);
    if (c > 8) {                       // wave-uniform (~7% of rows)
        gath8(src, e + 8, voff, 8, c, a0, a1);
        if (c > 16)                    // (~0.002% of rows)
            gath8(src, e + 16, voff, 16, c, a0, a1);
    }
    return make_float2(a0, a1);
}

// ---------------- pull SpMM over ELL: one wave per row, bf16 in/out
__global__ __launch_bounds__(256) void spmm_ell(
    const int* __restrict__ counts, const u32* __restrict__ ell,
    const u32* __restrict__ src, u32* __restrict__ dst)
{
    int wid = (blockIdx.x * 256 + threadIdx.x) >> 6;
    int r = __builtin_amdgcn_readfirstlane(wid);
    int lane = threadIdx.x & 63;
    float2 a = row_accum(r, lane * 4, counts, ell, src);
    dst[((size_t)r << 6) + lane] = pack2(a.x, a.y);
}

// ---------------- fused pass 3 + finalize + pos/neg gathers:
// rows = users | all items | pos | neg  ->  (ego + h1 + h2 + h3)/4
#define TOTW (2 * BATCHN + NITEMS + BATCHN)    // 52288 output rows
__global__ __launch_bounds__(256) void spmm3_finalize(
    const int* __restrict__ users, const int* __restrict__ pos,
    const int* __restrict__ neg,
    const int* __restrict__ counts, const u32* __restrict__ ell,
    const u32* __restrict__ ego,
    const u32* __restrict__ h1, const u32* __restrict__ h2,
    float* __restrict__ out)
{
    int wid = (blockIdx.x * 256 + threadIdx.x) >> 6;
    int w = __builtin_amdgcn_readfirstlane(wid);
    int lane = threadIdx.x & 63;
    int r, d;
    if (w < BATCHN)                        { r = users[w];                      d = w; }
    else if (w < BATCHN + NITEMS)          { int i = w - BATCHN;
                                             r = NUSERS + i;                   d = 3 * BATCHN + i; }
    else if (w < 2 * BATCHN + NITEMS)      { int i = w - BATCHN - NITEMS;
                                             r = NUSERS + pos[i];              d = BATCHN + i; }
    else                                   { int i = w - 2 * BATCHN - NITEMS;
                                             r = NUSERS + neg[i];              d = 2 * BATCHN + i; }
    float2 a = row_accum(r, lane * 4, counts, ell, h2);   // h3 row
    u32 g  = ego[((size_t)r << 6) + lane];                // bf16 ego (validated R14)
    u32 b1 = h1[((size_t)r << 6) + lane];
    u32 b2 = h2[((size_t)r << 6) + lane];
    float2 o;
    o.x = (lo2f(g) + lo2f(b1) + lo2f(b2) + a.x) * 0.25f;
    o.y = (hi2f(g) + hi2f(b1) + hi2f(b2) + a.y) * 0.25f;
    ((float2*)out + (size_t)d * 64)[lane] = o;
}

extern "C" void kernel_launch(void* const* d_in, const int* in_sizes, int n_in,
                              void* d_out, int out_size, void* d_ws, size_t ws_size,
                              hipStream_t stream)
{
    const int*   users = (const int*)d_in[0];
    const int*   pos   = (const int*)d_in[1];
    const int*   neg   = (const int*)d_in[2];
    const float* ue    = (const float*)d_in[3];
    const float* ie    = (const float*)d_in[4];
    const int*   arow  = (const int*)d_in[5];
    const int*   acol  = (const int*)d_in[6];
    const float* aval  = (const float*)d_in[7];

    const size_t hU = (size_t)NNODES * 64;        // u32 per bf16 node table
    char* ws = (char*)d_ws;
    u32*   h2     = (u32*)ws;   ws += hU * sizeof(u32);
    u32*   h1     = (u32*)ws;   ws += hU * sizeof(u32);
    u32*   ego    = (u32*)ws;   ws += hU * sizeof(u32);
    u32*   ell    = (u32*)ws;   ws += (size_t)NNODES * WELL * sizeof(u32);
    uint2* bkt    = (uint2*)ws; ws += (size_t)NBBLK * NBKT * SCAP * sizeof(uint2);
    int*   counts = (int*)ws;   ws += NNODES * sizeof(int);
    int*   scnt   = (int*)ws;   ws += NBBLK * NBKT * sizeof(int);

    // phase 1: deterministic bucket scatter || bf16 convert (no global state)
    bucket_convert<<<NBBLK + CVBLKS, 1024, 0, stream>>>(
        arow, acol, aval, scnt, bkt, ue, ie, ego);

    // phase 2: per-bucket ELL build (LDS counters, dense reads/writes)
    ell_from_buckets<<<NBUCK, 1024, 0, stream>>>(scnt, bkt, ell, counts);

    // passes 1-2: all rows; pass 3 fused with finalize + pos/neg
    spmm_ell<<<NNODES / 4, 256, 0, stream>>>(counts, ell, ego, h1);
    spmm_ell<<<NNODES / 4, 256, 0, stream>>>(counts, ell, h1, h2);

    spmm3_finalize<<<TOTW / 4, 256, 0, stream>>>(
        users, pos, neg, counts, ell, ego, h1, h2, (float*)d_out);
}